// Round 16
// baseline (199.105 us; speedup 1.0000x reference)
//
#include <hip/hip_runtime.h>
#include <hip/hip_cooperative_groups.h>
#include <math.h>

namespace cg = cooperative_groups;

// B=64, ROWS=7, COLS=7, D=1280, H=256, S=5, NEG=16, GRU_ROWS=6
// valid (s,r): r < 6-s -> 20 pairs; num_preds = 20*64*7 = 8960

typedef __bf16 bf16x8 __attribute__((ext_vector_type(8)));
typedef float  f32x4  __attribute__((ext_vector_type(4)));
typedef unsigned short u16;
typedef unsigned int u32;

__device__ inline u16 f2bf(float f) {           // RNE f32 -> bf16 bits
  unsigned int u = __float_as_uint(f);
  u += 0x7fff + ((u >> 16) & 1);
  return (u16)(u >> 16);
}

__device__ inline float bf2f(u16 b) {
  u32 u = (u32)b << 16;
  return __builtin_bit_cast(float, u);
}

__device__ inline void f2bf8(const float* s, u16* o) {
  float4 v0 = *(const float4*)s, v1 = *(const float4*)(s + 4);
  o[0] = f2bf(v0.x); o[1] = f2bf(v0.y); o[2] = f2bf(v0.z); o[3] = f2bf(v0.w);
  o[4] = f2bf(v1.x); o[5] = f2bf(v1.y); o[6] = f2bf(v1.z); o[7] = f2bf(v1.w);
}

__device__ inline bf16x8 lds_frag(const char* sm, int off) {
  return __builtin_bit_cast(bf16x8, *(const uint4*)(sm + off));
}

// async global->LDS 16B per lane (wave-uniform LDS base, per-lane global src)
__device__ inline void gld_lds16(const void* g, void* l) {
  __builtin_amdgcn_global_load_lds(
      (const __attribute__((address_space(1))) u32*)g,
      (__attribute__((address_space(3))) u32*)l, 16, 0, 0);
}

// fast transcendentals on the HW pipes (error ~1e-7, fine vs 0.5 threshold)
__device__ inline float fast_sigmoid(float x) {
  float t = __builtin_amdgcn_exp2f(-1.44269504f * x);
  return __builtin_amdgcn_rcpf(1.f + t);
}
__device__ inline float fast_tanh(float x) {
  float xc = fminf(fmaxf(x, -9.f), 9.f);
  float t = __builtin_amdgcn_exp2f(2.88539008f * xc);   // e^{2x}
  return (t - 1.f) * __builtin_amdgcn_rcpf(t + 1.f);
}
__device__ inline float fast_exp(float x) {
  return __builtin_amdgcn_exp2f(1.44269504f * x);
}
__device__ inline float fast_log(float x) {
  return __builtin_amdgcn_logf(x) * 0.69314718f;
}

#define MFMA16(a, b, c) __builtin_amdgcn_mfma_f32_16x16x32_bf16(a, b, c, 0, 0, 0)

// ---------------------------------------------------------------------------
// Phase 1 unit: pack work item `tid` (same mapping as round 14's pack_all).
// ---------------------------------------------------------------------------
__device__ __forceinline__ void pack_unit(
    int tid, const float* __restrict__ w_hh, const float* __restrict__ wk_w,
    const float* __restrict__ enc, const float* __restrict__ w_ih,
    u16* __restrict__ whhpk, u16* __restrict__ wkwpk, u16* __restrict__ epk,
    u16* __restrict__ enc2,  u16* __restrict__ wih2)
{
  int lane = tid & 63;
  u16 o[8];
  if (tid < 655360) {
    int f = tid >> 6;
    int ks2 = f & 1, t1 = f >> 1;
    int w = t1 & 3, t2 = t1 >> 2;
    int ch = t2 % 20, b = t2 / 20;
    int q = w * 16 + (lane & 15);
    int d = ch * 64 + ks2 * 32 + (lane >> 4) * 8;
    if (q < 49) {
      f2bf8(&enc[(size_t)(b * 49 + q) * 1280 + d], o);
    } else {
#pragma unroll
      for (int j = 0; j < 8; ++j) o[j] = 0;
    }
    *(uint4*)&epk[(size_t)f * 512 + lane * 8] = *(uint4*)o;
    if (q < 42) {                       // rows r<6 also live in enc2
      int r = q / 7, c = q - r * 7;
      int m = r * 448 + b * 7 + c;
      int by = m >> 7, row = m & 127;
      int k0 = d >> 6, slot = (d & 63) >> 3;
      int sl = slot ^ (row & 7);        // inverse-swizzle
      *(uint4*)&enc2[(size_t)((by * 20 + k0) * 1024 + row * 8 + sl) * 8] = *(uint4*)o;
    }
  } else if (tid < 679936) {
    int u = tid - 655360;
    int rest = u >> 6;
    int cb = rest >> 3, ks = rest & 7;
    int w = cb / 6, nf = cb % 6;
    int g = nf >> 1, half = nf & 1;
    int col = g * 256 + w * 32 + half * 16 + (lane & 15);
    int k = ks * 32 + (lane >> 4) * 8;
    f2bf8(&w_hh[(size_t)col * 256 + k], o);
    *(uint4*)&whhpk[(size_t)u * 8] = *(uint4*)o;
  } else if (tid < 884736) {
    int u = tid - 679936;
    int f = u >> 6;
    int ks = f & 7, t1 = f >> 3;
    int w = t1 & 3, t2 = t1 >> 2;
    int ch = t2 % 20, s = t2 / 20;
    f2bf8(&wk_w[((size_t)s * 1280 + ch * 64 + w * 16 + (lane & 15)) * 256
                + ks * 32 + (lane >> 4) * 8], o);
    *(uint4*)&wkwpk[(size_t)f * 512 + lane * 8] = *(uint4*)o;
  } else if (tid < 1007616) {
    int u = tid - 884736;
    int unit = u & 1023;
    int row = unit >> 3, sl = unit & 7;
    int tk = u >> 10;
    int k0 = tk % 20, bx = tk / 20;
    int slot = sl ^ (row & 7);
    f2bf8(&w_ih[(size_t)(bx * 128 + row) * 1280 + k0 * 64 + slot * 8], o);
    *(uint4*)&wih2[(size_t)u * 8] = *(uint4*)o;
  }
}

// ---------------------------------------------------------------------------
// Phase 2: gi = enc @ w_ih^T + b_ih. 126 logical tiles (bx 0..5, by 0..20),
// 512 threads = 8 waves (4 row x 2 col of 32x64), double-buffered
// global_load_lds staging with counted vmcnt (4 ops/thread/stage).
// ---------------------------------------------------------------------------
__device__ __forceinline__ void gi_body(
    char* sm, int bid, int t,
    const u16* __restrict__ enc2, const u16* __restrict__ wih2,
    const float* __restrict__ b_ih, u16* __restrict__ gib)
{
  const int bx = bid % 6, by = bid / 6;
  const int lane = t & 63, w = t >> 6;
  const int wr = w >> 1, wc = w & 1;   // wr 0..3 (32 rows), wc 0..1 (64 cols)
  const int wu = t & ~63;

  f32x4 acc[2][4];
#pragma unroll
  for (int i = 0; i < 2; ++i)
#pragma unroll
    for (int j = 0; j < 4; ++j) acc[i][j] = (f32x4){0.f, 0.f, 0.f, 0.f};

  const char* ga0 = (const char*)enc2 + ((size_t)(by * 20) << 14);
  const char* gb0 = (const char*)wih2 + ((size_t)(bx * 20) << 14);

  // prologue: stage chunk 0 into buffer 0 (4 vm ops per thread)
#pragma unroll
  for (int j = 0; j < 2; ++j) {
    gld_lds16(ga0 + (j * 512 + t) * 16, sm + (j * 512 + wu) * 16);
    gld_lds16(gb0 + (j * 512 + t) * 16, sm + 16384 + (j * 512 + wu) * 16);
  }

  for (int k0c = 0; k0c < 20; ++k0c) {
    char* cur = sm + (k0c & 1) * 32768;
    if (k0c + 1 < 20) {
      char* nxt = sm + ((k0c + 1) & 1) * 32768;
      const char* ga = ga0 + ((size_t)(k0c + 1) << 14);
      const char* gb = gb0 + ((size_t)(k0c + 1) << 14);
#pragma unroll
      for (int j = 0; j < 2; ++j) {
        gld_lds16(ga + (j * 512 + t) * 16, nxt + (j * 512 + wu) * 16);
        gld_lds16(gb + (j * 512 + t) * 16, nxt + 16384 + (j * 512 + wu) * 16);
      }
      asm volatile("s_waitcnt vmcnt(4)" ::: "memory");   // k's 4 landed
    } else {
      asm volatile("s_waitcnt vmcnt(0)" ::: "memory");
    }
    __builtin_amdgcn_s_barrier();

#pragma unroll
    for (int ks = 0; ks < 2; ++ks) {
      bf16x8 a[2], b[4];
#pragma unroll
      for (int i = 0; i < 2; ++i) {
        int arow = wr * 32 + i * 16 + (lane & 15);
        int akb  = (ks * 64 + (lane >> 4) * 16) ^ ((arow & 7) << 4);
        a[i] = lds_frag(cur, arow * 128 + akb);
      }
#pragma unroll
      for (int jn = 0; jn < 4; ++jn) {
        int brow = wc * 64 + jn * 16 + (lane & 15);
        int bkb  = (ks * 64 + (lane >> 4) * 16) ^ ((brow & 7) << 4);
        b[jn] = lds_frag(cur + 16384, brow * 128 + bkb);
      }
#pragma unroll
      for (int i = 0; i < 2; ++i)
#pragma unroll
        for (int jn = 0; jn < 4; ++jn)
          acc[i][jn] = MFMA16(a[i], b[jn], acc[i][jn]);
    }
    __builtin_amdgcn_s_barrier();     // reads of cur done before overwrite
  }

#pragma unroll
  for (int i = 0; i < 2; ++i)
#pragma unroll
    for (int jn = 0; jn < 4; ++jn) {
      int gcol = bx * 128 + wc * 64 + jn * 16 + (lane & 15);
      float bias = b_ih[gcol];
#pragma unroll
      for (int r4 = 0; r4 < 4; ++r4) {
        int grow = by * 128 + wr * 32 + i * 16 + (lane >> 4) * 4 + r4;
        gib[(size_t)grow * 768 + gcol] = f2bf(acc[i][jn][r4] + bias);
      }
    }
}

// ---------------------------------------------------------------------------
// Phase 3: GRU (blocks 0..27, 512 thr, 16 seqs). Circular cross-step weight
// pipeline, gi LDS dbuf, in-register pointwise.
// ---------------------------------------------------------------------------
__device__ __forceinline__ void gru_body(
    char* sm, int bid, int t,
    const u16* __restrict__ whh_pk, const float* __restrict__ b_hh,
    const float* __restrict__ hidden, const u16* __restrict__ gib,
    u16* __restrict__ ctxb)
{
  const int n0 = bid * 16;
  const int lane = t & 63, w = t >> 6;
  const int GI0 = 16384;

  const int l15 = lane & 15;
  const int seq0 = (lane >> 4) * 4;
  const int hc0 = w * 32 + l15, hc1 = w * 32 + 16 + l15;

  const float br0 = b_hh[hc0],       br1 = b_hh[hc1];
  const float bz0 = b_hh[256 + hc0], bz1 = b_hh[256 + hc1];
  const float bn0 = b_hh[512 + hc0], bn1 = b_hh[512 + hc1];

#pragma unroll
  for (int i = 0; i < 3; ++i) {
    int chunk = w * 3 + i;
    gld_lds16(gib + (size_t)n0 * 768 + chunk * 512 + lane * 8,
              sm + GI0 + chunk * 1024);
  }

  float hold[2][4];
  {
    float h0 = hidden[hc0], h1 = hidden[hc1];
#pragma unroll
    for (int r4 = 0; r4 < 4; ++r4) { hold[0][r4] = h0; hold[1][r4] = h1; }
    u16 hb0 = f2bf(h0), hb1 = f2bf(h1);
#pragma unroll
    for (int r4 = 0; r4 < 4; ++r4) {
      int seq = seq0 + r4;
      *(u16*)(sm + seq * 512 + ((hc0 * 2) ^ ((seq & 7) << 4))) = hb0;
      *(u16*)(sm + seq * 512 + ((hc1 * 2) ^ ((seq & 7) << 4))) = hb1;
    }
  }

  // one-time pipeline fill: slots 0..2 <- ks 0..2
  bf16x8 bP[3][6];
  {
    const char* pkb0 = (const char*)whh_pk + w * 49152 + lane * 16;
#pragma unroll
    for (int j = 0; j < 3; ++j)
#pragma unroll
      for (int nf = 0; nf < 6; ++nf)
        bP[j][nf] = *(const bf16x8*)(pkb0 + nf * 8192 + j * 1024);
  }
  __syncthreads();

  for (int r = 0; r < 6; ++r) {
    const char* hb  = sm + (r & 1) * 8192;
    char* hbn       = sm + ((r + 1) & 1) * 8192;
    const char* gbr = sm + GI0 + (r & 1) * 24576;

    uintptr_t pa = (uintptr_t)whh_pk;
    asm volatile("" : "+v"(pa));        // defeat cross-step load hoisting
    const char* pkb = (const char*)pa + w * 49152 + lane * 16;

    f32x4 acc[6];
#pragma unroll
    for (int nf = 0; nf < 6; ++nf) acc[nf] = (f32x4){0.f, 0.f, 0.f, 0.f};

#pragma unroll
    for (int ks = 0; ks < 8; ++ks) {
      const int slot = ks % 3;
      bf16x8 a = lds_frag(hb, l15 * 512 +
                          ((ks * 64 + (lane >> 4) * 16) ^ ((l15 & 7) << 4)));
#pragma unroll
      for (int nf = 0; nf < 6; ++nf) acc[nf] = MFMA16(a, bP[slot][nf], acc[nf]);
      {
        const int nk = (ks + 3) & 7;    // circular: 5,6,7 refill next step's 0,1,2
#pragma unroll
        for (int nf = 0; nf < 6; ++nf)
          bP[slot][nf] = *(const bf16x8*)(pkb + nf * 8192 + nk * 1024);
      }
    }

    if (r + 1 < 6) {
#pragma unroll
      for (int i = 0; i < 3; ++i) {
        int chunk = w * 3 + i;
        gld_lds16(gib + (size_t)((r + 1) * 448 + n0) * 768 + chunk * 512 + lane * 8,
                  sm + GI0 + ((r + 1) & 1) * 24576 + chunk * 1024);
      }
    }

#pragma unroll
    for (int r4 = 0; r4 < 4; ++r4) {
      int seq = seq0 + r4;
      float ir0 = bf2f(*(const u16*)(gbr + (size_t)(seq * 768 + hc0) * 2));
      float iz0 = bf2f(*(const u16*)(gbr + (size_t)(seq * 768 + 256 + hc0) * 2));
      float in0 = bf2f(*(const u16*)(gbr + (size_t)(seq * 768 + 512 + hc0) * 2));
      float ir1 = bf2f(*(const u16*)(gbr + (size_t)(seq * 768 + hc1) * 2));
      float iz1 = bf2f(*(const u16*)(gbr + (size_t)(seq * 768 + 256 + hc1) * 2));
      float in1 = bf2f(*(const u16*)(gbr + (size_t)(seq * 768 + 512 + hc1) * 2));
      {
        float rg = fast_sigmoid(ir0 + acc[0][r4] + br0);
        float zg = fast_sigmoid(iz0 + acc[2][r4] + bz0);
        float ng = fast_tanh(in0 + rg * (acc[4][r4] + bn0));
        float hnew = (1.f - zg) * ng + zg * hold[0][r4];
        hold[0][r4] = hnew;
        u16 hb16 = f2bf(hnew);
        *(u16*)(hbn + seq * 512 + ((hc0 * 2) ^ ((seq & 7) << 4))) = hb16;
        ctxb[(size_t)(r * 448 + n0 + seq) * 256 + hc0] = hb16;
      }
      {
        float rg = fast_sigmoid(ir1 + acc[1][r4] + br1);
        float zg = fast_sigmoid(iz1 + acc[3][r4] + bz1);
        float ng = fast_tanh(in1 + rg * (acc[5][r4] + bn1));
        float hnew = (1.f - zg) * ng + zg * hold[1][r4];
        hold[1][r4] = hnew;
        u16 hb16 = f2bf(hnew);
        *(u16*)(hbn + seq * 512 + ((hc1 * 2) ^ ((seq & 7) << 4))) = hb16;
        ctxb[(size_t)(r * 448 + n0 + seq) * 256 + hc1] = hb16;
      }
    }
    __syncthreads();
  }
}

// ---------------------------------------------------------------------------
// Phase 4: preds+dots+loss for one (b,s). 512 threads: waves 0..3 compute,
// waves 4..7 barrier-only. Static MF. TRAILING BARRIER (round-16 fix):
// blocks chaining two pd tiles raced — wave 0 still reading dtile (loss)
// while waves 1..7 staged the next tile's ctx into the same LDS region.
// ---------------------------------------------------------------------------
template<int MF>
__device__ __forceinline__ void pd_body(
    int b, int s, int Ms, int t, int lane, int w, char* sm,
    const u16* __restrict__ ctxb, const u16* __restrict__ wkwpk,
    const float* __restrict__ wk_b, const u16* __restrict__ epk,
    const int* __restrict__ neg_rows, const int* __restrict__ neg_cols,
    float* __restrict__ out)
{
  const int PT_OFF = 24576;
  const bool act = (w < 4);           // wave-uniform compute guard

  // ctx stage uses all 512 threads (1536 units)
#pragma unroll
  for (int j = 0; j < 3; ++j) {
    int u = j * 512 + t;
    int row = u >> 5, slot = u & 31;
    int rr = row < Ms ? row : 0;
    int r = rr / 7, c = rr - r * 7;
    uint4 v = *(const uint4*)&ctxb[((size_t)(r * 448 + b * 7 + c)) * 256 + slot * 8];
    int off = row * 512 + ((slot * 16) ^ ((row & 7) << 4));
    *(uint4*)(sm + off) = v;
  }
  __syncthreads();

  bf16x8 a1[MF][8];
  if (act) {
#pragma unroll
    for (int m = 0; m < MF; ++m)
#pragma unroll
      for (int ks = 0; ks < 8; ++ks) {
        int row = m * 16 + (lane & 15);
        int kb  = (ks * 64 + (lane >> 4) * 16) ^ ((row & 7) << 4);
        a1[m][ks] = lds_frag(sm, row * 512 + kb);
      }
  }

  f32x4 acc2[MF];
#pragma unroll
  for (int m = 0; m < MF; ++m) acc2[m] = (f32x4){0.f, 0.f, 0.f, 0.f};

  const char* wfB = (const char*)wkwpk + ((size_t)(s * 20) * 4 + (w & 3)) * 8192 + lane * 16;
  const char* efB = (const char*)epk   + ((size_t)(b * 20) * 4 + (w & 3)) * 2048 + lane * 16;
  const int colL = (w & 3) * 16 + (lane & 15);

  bf16x8 wF[8];
  if (act) {
#pragma unroll
    for (int ks = 0; ks < 8; ++ks)
      wF[ks] = *(const bf16x8*)(wfB + ks * 1024);
  }

  for (int ch = 0; ch < 20; ++ch) {
    char* pt = sm + PT_OFF + (ch & 1) * 6144;
    bf16x8 e0{}, e1{};

    if (act) {
      f32x4 acc1[MF];
#pragma unroll
      for (int m = 0; m < MF; ++m) acc1[m] = (f32x4){0.f, 0.f, 0.f, 0.f};
#pragma unroll
      for (int ks = 0; ks < 8; ++ks) {
#pragma unroll
        for (int m = 0; m < MF; ++m) acc1[m] = MFMA16(a1[m][ks], wF[ks], acc1[m]);
      }
      if (ch + 1 < 20) {
        const char* wfn = wfB + (size_t)(ch + 1) * 4 * 8192;
#pragma unroll
        for (int ks = 0; ks < 8; ++ks)
          wF[ks] = *(const bf16x8*)(wfn + ks * 1024);
      }
      float bias = wk_b[s * 1280 + ch * 64 + colL];
#pragma unroll
      for (int m = 0; m < MF; ++m)
#pragma unroll
        for (int r4 = 0; r4 < 4; ++r4) {
          float p = acc1[m][r4] + bias;
          p = fminf(fmaxf(p, -1.f), 1.f);
          int prow = m * 16 + (lane >> 4) * 4 + r4;
          *(u16*)(pt + prow * 128 + ((colL * 2) ^ ((prow & 7) << 4))) = f2bf(p);
        }
      const char* ef = efB + (size_t)ch * 4 * 2048;
      e0 = *(const bf16x8*)ef;
      e1 = *(const bf16x8*)(ef + 1024);
    }
    __syncthreads();   // Pt[ch&1] visible (all 8 waves participate)

    if (act) {
#pragma unroll
      for (int m = 0; m < MF; ++m) {
        int prow = m * 16 + (lane & 15);
        bf16x8 pf0 = lds_frag(pt, prow * 128 +
                              (((lane >> 4) * 16) ^ ((prow & 7) << 4)));
        acc2[m] = MFMA16(pf0, e0, acc2[m]);
        bf16x8 pf1 = lds_frag(pt, prow * 128 +
                              ((64 + (lane >> 4) * 16) ^ ((prow & 7) << 4)));
        acc2[m] = MFMA16(pf1, e1, acc2[m]);
      }
    }
  }

  float* dtile = (float*)sm;
  if (act) {
#pragma unroll
    for (int m = 0; m < MF; ++m)
#pragma unroll
      for (int r4 = 0; r4 < 4; ++r4) {
        int row = m * 16 + (lane >> 4) * 4 + r4;
        int q = (w & 3) * 16 + (lane & 15);
        dtile[row * 65 + q] = acc2[m][r4];
      }
  }
  __syncthreads();

  if (w == 0) {
    float lsum = 0.f, csum = 0.f;
    if (lane < Ms) {
      int rr = lane;
      int r = rr / 7, c = rr - r * 7;
      const float* drow = &dtile[rr * 65];
      float d0 = drow[rr];
      const int nbase = (((b * 5 + s) * 6 + r) * 7 + c) * 16;
      float mx = d0;
      float d[16];
#pragma unroll
      for (int j = 0; j < 16; ++j) {
        int q = neg_rows[nbase + j] * 7 + neg_cols[nbase + j];
        d[j] = drow[q];
        mx = fmaxf(mx, d[j]);
      }
      float se = fast_exp(d0 - mx);
#pragma unroll
      for (int j = 0; j < 16; ++j) se += fast_exp(d[j] - mx);
      lsum = -(d0 - mx - fast_log(se));
      csum = (d0 >= mx) ? 1.f : 0.f;
    }
#pragma unroll
    for (int off = 32; off > 0; off >>= 1) {
      lsum += __shfl_down(lsum, off);
      csum += __shfl_down(csum, off);
    }
    if (lane == 0) {
      atomicAdd(&out[0], lsum * (1.f / 8960.f));
      atomicAdd(&out[1], csum * (1.f / 8960.f));
    }
  }
  __syncthreads();   // ROUND-16 FIX: dtile reads complete before the next
                     // pd tile's ctx staging overwrites this LDS region
}

__device__ __forceinline__ void pd_run(
    int b, int s, char* sm, int t,
    const u16* __restrict__ ctxb, const u16* __restrict__ wkwpk,
    const float* __restrict__ wk_b, const u16* __restrict__ epk,
    const int* __restrict__ neg_rows, const int* __restrict__ neg_cols,
    float* __restrict__ out)
{
  const int Ms = (6 - s) * 7;
  const int lane = t & 63, w = t >> 6;
  if (s < 2)      pd_body<3>(b, s, Ms, t, lane, w, sm, ctxb, wkwpk, wk_b, epk,
                             neg_rows, neg_cols, out);
  else if (s < 4) pd_body<2>(b, s, Ms, t, lane, w, sm, ctxb, wkwpk, wk_b, epk,
                             neg_rows, neg_cols, out);
  else            pd_body<1>(b, s, Ms, t, lane, w, sm, ctxb, wkwpk, wk_b, epk,
                             neg_rows, neg_cols, out);
}

// ---------------------------------------------------------------------------
// The cooperative mega-kernel: 256 blocks x 512 threads, 64KB dynamic LDS,
// grid.sync between phases (replaces 3 kernel-boundary drains).
// ---------------------------------------------------------------------------
__global__ void __launch_bounds__(512) mega(
    const float* __restrict__ w_hh, const float* __restrict__ wk_w,
    const float* __restrict__ enc,  const float* __restrict__ w_ih,
    const float* __restrict__ b_ih, const float* __restrict__ b_hh,
    const float* __restrict__ hidden, const float* __restrict__ wk_b,
    const int* __restrict__ neg_rows, const int* __restrict__ neg_cols,
    u16* __restrict__ whhpk, u16* __restrict__ wkwpk, u16* __restrict__ epk,
    u16* __restrict__ enc2,  u16* __restrict__ wih2,
    u16* __restrict__ gib,   u16* __restrict__ ctxb, float* __restrict__ out)
{
  extern __shared__ char sm[];
  cg::grid_group grid = cg::this_grid();
  const int bid = blockIdx.x;   // 0..255
  const int t = threadIdx.x;    // 0..511

  // ---- phase 1: pack (grid-stride over 1,007,616 units) ----
  if (bid == 0 && t == 0) { out[0] = 0.f; out[1] = 0.f; }
#pragma unroll
  for (int it = 0; it < 8; ++it) {
    int tid = it * 131072 + bid * 512 + t;
    if (tid < 1007616)
      pack_unit(tid, w_hh, wk_w, enc, w_ih, whhpk, wkwpk, epk, enc2, wih2);
  }
  grid.sync();

  // ---- phase 2: gi GEMM (126 logical tiles) ----
  if (bid < 126)
    gi_body(sm, bid, t, enc2, wih2, b_ih, gib);
  grid.sync();

  // ---- phase 3: GRU (28 logical blocks) ----
  if (bid < 28)
    gru_body(sm, bid, t, whhpk, b_hh, hidden, gib, ctxb);
  grid.sync();

  // ---- phase 4: preds+dots+loss (320 logical tiles over 256 blocks) ----
  {
    int s = bid >> 6;           // 0..3
    int b = bid & 63;
    pd_run(b, s, sm, t, ctxb, wkwpk, wk_b, epk, neg_rows, neg_cols, out);
    if (bid >= 192)             // pair lightest (s=4, MF=1) with s=3 blocks
      pd_run(bid - 192, 4, sm, t, ctxb, wkwpk, wk_b, epk, neg_rows, neg_cols, out);
  }
}

// ---------------------------------------------------------------------------
extern "C" void kernel_launch(void* const* d_in, const int* in_sizes, int n_in,
                              void* d_out, int out_size, void* d_ws, size_t ws_size,
                              hipStream_t stream)
{
  const float* enc    = (const float*)d_in[0];
  const float* hidden = (const float*)d_in[1];
  const float* w_ih   = (const float*)d_in[2];
  const float* w_hh   = (const float*)d_in[3];
  const float* b_ih   = (const float*)d_in[4];
  const float* b_hh   = (const float*)d_in[5];
  const float* wk_w   = (const float*)d_in[6];
  const float* wk_b   = (const float*)d_in[7];
  const int* neg_rows = (const int*)d_in[8];
  const int* neg_cols = (const int*)d_in[9];
  float* out = (float*)d_out;

  u16*   gib   = (u16*)d_ws;                        // [6*448][768] bf16
  u16*   ctxb  = gib + 6 * 448 * 768;               // [6*448][256] bf16
  u16*   whhpk = ctxb + 6 * 448 * 256;              // 196608 bf16
  u16*   wkwpk = whhpk + 24576 * 8;                 // 1638400 bf16
  u16*   epk   = wkwpk + 204800 * 8;                // 5242880 bf16
  u16*   enc2  = epk + 655360 * 8;                  // 3440640 bf16
  u16*   wih2  = enc2 + 430080 * 8;                 // 983040 bf16

  void* args[] = {
    (void*)&w_hh, (void*)&wk_w, (void*)&enc, (void*)&w_ih,
    (void*)&b_ih, (void*)&b_hh, (void*)&hidden, (void*)&wk_b,
    (void*)&neg_rows, (void*)&neg_cols,
    (void*)&whhpk, (void*)&wkwpk, (void*)&epk, (void*)&enc2, (void*)&wih2,
    (void*)&gib, (void*)&ctxb, (void*)&out
  };
  hipLaunchCooperativeKernel((const void*)mega, dim3(256), dim3(512),
                             args, 65536, stream);
}

// Round 17
// 86.422 us; speedup vs baseline: 2.3039x; 2.3039x over previous
//
#include <hip/hip_runtime.h>
#include <math.h>

// B=64, ROWS=7, COLS=7, D=1280, H=256, S=5, NEG=16, GRU_ROWS=6
// valid (s,r): r < 6-s -> 20 pairs; num_preds = 20*64*7 = 8960

typedef __bf16 bf16x8 __attribute__((ext_vector_type(8)));
typedef float  f32x4  __attribute__((ext_vector_type(4)));
typedef unsigned short u16;
typedef unsigned int u32;

__device__ inline u16 f2bf(float f) {           // RNE f32 -> bf16 bits
  unsigned int u = __float_as_uint(f);
  u += 0x7fff + ((u >> 16) & 1);
  return (u16)(u >> 16);
}

__device__ inline float bf2f(u16 b) {
  u32 u = (u32)b << 16;
  return __builtin_bit_cast(float, u);
}

__device__ inline void f2bf8(const float* s, u16* o) {
  float4 v0 = *(const float4*)s, v1 = *(const float4*)(s + 4);
  o[0] = f2bf(v0.x); o[1] = f2bf(v0.y); o[2] = f2bf(v0.z); o[3] = f2bf(v0.w);
  o[4] = f2bf(v1.x); o[5] = f2bf(v1.y); o[6] = f2bf(v1.z); o[7] = f2bf(v1.w);
}

__device__ inline bf16x8 lds_frag(const char* sm, int off) {
  return __builtin_bit_cast(bf16x8, *(const uint4*)(sm + off));
}

// async global->LDS 16B per lane (wave-uniform LDS base, per-lane global src)
__device__ inline void gld_lds16(const void* g, void* l) {
  __builtin_amdgcn_global_load_lds(
      (const __attribute__((address_space(1))) u32*)g,
      (__attribute__((address_space(3))) u32*)l, 16, 0, 0);
}

// fast transcendentals on the HW pipes (error ~1e-7, fine vs 0.5 threshold)
__device__ inline float fast_sigmoid(float x) {
  float t = __builtin_amdgcn_exp2f(-1.44269504f * x);
  return __builtin_amdgcn_rcpf(1.f + t);
}
__device__ inline float fast_tanh(float x) {
  float xc = fminf(fmaxf(x, -9.f), 9.f);
  float t = __builtin_amdgcn_exp2f(2.88539008f * xc);   // e^{2x}
  return (t - 1.f) * __builtin_amdgcn_rcpf(t + 1.f);
}
__device__ inline float fast_exp(float x) {
  return __builtin_amdgcn_exp2f(1.44269504f * x);
}
__device__ inline float fast_log(float x) {
  return __builtin_amdgcn_logf(x) * 0.69314718f;
}

#define MFMA16(a, b, c) __builtin_amdgcn_mfma_f32_16x16x32_bf16(a, b, c, 0, 0, 0)

// ---------------------------------------------------------------------------
// packA: ONLY what gi_mfma needs — enc2 (pre-swizzled A tiles) + wih2
// (pre-swizzled B tiles). 552960 units. Also zeroes out[2].
// ---------------------------------------------------------------------------
__global__ __launch_bounds__(256) void packA(
    const float* __restrict__ enc, const float* __restrict__ w_ih,
    u16* __restrict__ enc2, u16* __restrict__ wih2, float* __restrict__ out)
{
  int tid = blockIdx.x * 256 + threadIdx.x;
  if (tid == 0) { out[0] = 0.f; out[1] = 0.f; }
  u16 o[8];
  if (tid < 430080) {
    int u = tid;                               // (by*20+k0)*1024 + row*8 + sl
    int unit = u & 1023;
    int row = unit >> 3, sl = unit & 7;
    int tk = u >> 10;
    int k0 = tk % 20, by = tk / 20;
    int m = by * 128 + row;
    int r = m / 448, n = m - r * 448;
    int b = n / 7, c = n - b * 7;
    int slot = sl ^ (row & 7);                 // inverse-swizzle the source
    f2bf8(&enc[(size_t)(b * 49 + r * 7 + c) * 1280 + k0 * 64 + slot * 8], o);
    *(uint4*)&enc2[(size_t)u * 8] = *(uint4*)o;
  } else if (tid < 552960) {
    int u = tid - 430080;                      // (bx*20+k0)*1024 + row*8 + sl
    int unit = u & 1023;
    int row = unit >> 3, sl = unit & 7;
    int tk = u >> 10;
    int k0 = tk % 20, bx = tk / 20;
    int slot = sl ^ (row & 7);
    f2bf8(&w_ih[(size_t)(bx * 128 + row) * 1280 + k0 * 64 + slot * 8], o);
    *(uint4*)&wih2[(size_t)u * 8] = *(uint4*)o;
  }
}

// ---------------------------------------------------------------------------
// gi_packB: ONE launch, two roles (block-uniform branch).
//  blocks 0..125: gi = enc @ w_ih^T + b_ih (round-14 structure: 128x128 tile,
//    4 waves 2x2, double-buffered global_load_lds, counted vmcnt(8)).
//  blocks 126..3581: packB — whhpk / wkwpk / epk (consumed only by gru/pd,
//    which launch AFTER this kernel) — fills the ~130 CUs gi leaves idle.
// ---------------------------------------------------------------------------
__global__ __launch_bounds__(256) void gi_packB(
    const u16* __restrict__ enc2, const u16* __restrict__ wih2,
    const float* __restrict__ b_ih, u16* __restrict__ gib,
    const float* __restrict__ w_hh, const float* __restrict__ wk_w,
    const float* __restrict__ enc,
    u16* __restrict__ whhpk, u16* __restrict__ wkwpk, u16* __restrict__ epk)
{
  __shared__ char sm[65536];        // 2 x (A 16KB | B 16KB) — gi blocks only
  const int bid = blockIdx.x;
  const int t = threadIdx.x;

  if (bid >= 126) {
    // ---------------- packB ----------------
    int tid = (bid - 126) * 256 + t;           // 0..884735
    int lane = tid & 63;
    u16 o[8];
    if (tid < 655360) {
      int f = tid >> 6;
      int ks2 = f & 1, t1 = f >> 1;
      int w = t1 & 3, t2 = t1 >> 2;
      int ch = t2 % 20, b = t2 / 20;
      int q = w * 16 + (lane & 15);
      int d = ch * 64 + ks2 * 32 + (lane >> 4) * 8;
      if (q < 49) {
        f2bf8(&enc[(size_t)(b * 49 + q) * 1280 + d], o);
      } else {
#pragma unroll
        for (int j = 0; j < 8; ++j) o[j] = 0;
      }
      *(uint4*)&epk[(size_t)f * 512 + lane * 8] = *(uint4*)o;
    } else if (tid < 679936) {
      int u = tid - 655360;
      int rest = u >> 6;
      int cb = rest >> 3, ks = rest & 7;
      int w = cb / 6, nf = cb % 6;
      int g = nf >> 1, half = nf & 1;
      int col = g * 256 + w * 32 + half * 16 + (lane & 15);
      int k = ks * 32 + (lane >> 4) * 8;
      f2bf8(&w_hh[(size_t)col * 256 + k], o);
      *(uint4*)&whhpk[(size_t)u * 8] = *(uint4*)o;
    } else if (tid < 884736) {
      int u = tid - 679936;
      int f = u >> 6;
      int ks = f & 7, t1 = f >> 3;
      int w = t1 & 3, t2 = t1 >> 2;
      int ch = t2 % 20, s = t2 / 20;
      f2bf8(&wk_w[((size_t)s * 1280 + ch * 64 + w * 16 + (lane & 15)) * 256
                  + ks * 32 + (lane >> 4) * 8], o);
      *(uint4*)&wkwpk[(size_t)f * 512 + lane * 8] = *(uint4*)o;
    }
    return;
  }

  // ---------------- gi tile (round-14 structure) ----------------
  const int bx = bid % 6, by = bid / 6;
  const int lane = t & 63, w = t >> 6;
  const int wr = w >> 1, wc = w & 1;
  const int wu = t & ~63;

  f32x4 acc[4][4];
#pragma unroll
  for (int i = 0; i < 4; ++i)
#pragma unroll
    for (int j = 0; j < 4; ++j) acc[i][j] = (f32x4){0.f, 0.f, 0.f, 0.f};

  const char* ga0 = (const char*)enc2 + ((size_t)(by * 20) << 14);
  const char* gb0 = (const char*)wih2 + ((size_t)(bx * 20) << 14);

  // prologue: stage chunk 0 into buffer 0 (8 vm ops per thread)
#pragma unroll
  for (int j = 0; j < 4; ++j) {
    gld_lds16(ga0 + (j * 256 + t) * 16, sm + (j * 256 + wu) * 16);
    gld_lds16(gb0 + (j * 256 + t) * 16, sm + 16384 + (j * 256 + wu) * 16);
  }

  for (int k0c = 0; k0c < 20; ++k0c) {
    char* cur = sm + (k0c & 1) * 32768;
    if (k0c + 1 < 20) {
      char* nxt = sm + ((k0c + 1) & 1) * 32768;
      const char* ga = ga0 + ((size_t)(k0c + 1) << 14);
      const char* gb = gb0 + ((size_t)(k0c + 1) << 14);
#pragma unroll
      for (int j = 0; j < 4; ++j) {
        gld_lds16(ga + (j * 256 + t) * 16, nxt + (j * 256 + wu) * 16);
        gld_lds16(gb + (j * 256 + t) * 16, nxt + 16384 + (j * 256 + wu) * 16);
      }
      asm volatile("s_waitcnt vmcnt(8)" ::: "memory");   // k's 8 landed
    } else {
      asm volatile("s_waitcnt vmcnt(0)" ::: "memory");   // last chunk
    }
    __builtin_amdgcn_s_barrier();

#pragma unroll
    for (int ks = 0; ks < 2; ++ks) {
      bf16x8 a[4], b[4];
#pragma unroll
      for (int i = 0; i < 4; ++i) {
        int arow = wr * 64 + i * 16 + (lane & 15);
        int akb  = (ks * 64 + (lane >> 4) * 16) ^ ((arow & 7) << 4);
        a[i] = lds_frag(cur, arow * 128 + akb);
        int brow = wc * 64 + i * 16 + (lane & 15);
        int bkb  = (ks * 64 + (lane >> 4) * 16) ^ ((brow & 7) << 4);
        b[i] = lds_frag(cur + 16384, brow * 128 + bkb);
      }
#pragma unroll
      for (int i = 0; i < 4; ++i)
#pragma unroll
        for (int jn = 0; jn < 4; ++jn)
          acc[i][jn] = MFMA16(a[i], b[jn], acc[i][jn]);
    }
    __builtin_amdgcn_s_barrier();     // all reads of cur done before overwrite
  }

#pragma unroll
  for (int i = 0; i < 4; ++i)
#pragma unroll
    for (int jn = 0; jn < 4; ++jn) {
      int gcol = bx * 128 + wc * 64 + jn * 16 + (lane & 15);
      float bias = b_ih[gcol];
#pragma unroll
      for (int r4 = 0; r4 < 4; ++r4) {
        int grow = by * 128 + wr * 64 + i * 16 + (lane >> 4) * 4 + r4;
        gib[(size_t)grow * 768 + gcol] = f2bf(acc[i][jn][r4] + bias);
      }
    }
}

// ---------------------------------------------------------------------------
// GRU (round-14, unchanged): circular cross-step weight pipeline, gi LDS
// dbuf, in-register pointwise, one barrier/step.
// ---------------------------------------------------------------------------
__global__ __launch_bounds__(512) void gru_fused(
    const u16* __restrict__ whh_pk, const float* __restrict__ b_hh,
    const float* __restrict__ hidden, const u16* __restrict__ gib,
    u16* __restrict__ ctxb)
{
  const int n0 = blockIdx.x * 16;
  const int t = threadIdx.x, lane = t & 63, w = t >> 6;

  __shared__ char sm[16384 + 2 * 24576];   // h dbuf 2x8KB | gi dbuf 2x24KB
  const int GI0 = 16384;

  const int l15 = lane & 15;
  const int seq0 = (lane >> 4) * 4;
  const int hc0 = w * 32 + l15, hc1 = w * 32 + 16 + l15;

  const float br0 = b_hh[hc0],       br1 = b_hh[hc1];
  const float bz0 = b_hh[256 + hc0], bz1 = b_hh[256 + hc1];
  const float bn0 = b_hh[512 + hc0], bn1 = b_hh[512 + hc1];

#pragma unroll
  for (int i = 0; i < 3; ++i) {
    int chunk = w * 3 + i;
    gld_lds16(gib + (size_t)n0 * 768 + chunk * 512 + lane * 8,
              sm + GI0 + chunk * 1024);
  }

  float hold[2][4];
  {
    float h0 = hidden[hc0], h1 = hidden[hc1];
#pragma unroll
    for (int r4 = 0; r4 < 4; ++r4) { hold[0][r4] = h0; hold[1][r4] = h1; }
    u16 hb0 = f2bf(h0), hb1 = f2bf(h1);
#pragma unroll
    for (int r4 = 0; r4 < 4; ++r4) {
      int seq = seq0 + r4;
      *(u16*)(sm + seq * 512 + ((hc0 * 2) ^ ((seq & 7) << 4))) = hb0;
      *(u16*)(sm + seq * 512 + ((hc1 * 2) ^ ((seq & 7) << 4))) = hb1;
    }
  }

  // one-time pipeline fill: slots 0..2 <- ks 0..2
  bf16x8 bP[3][6];
  {
    const char* pkb0 = (const char*)whh_pk + w * 49152 + lane * 16;
#pragma unroll
    for (int j = 0; j < 3; ++j)
#pragma unroll
      for (int nf = 0; nf < 6; ++nf)
        bP[j][nf] = *(const bf16x8*)(pkb0 + nf * 8192 + j * 1024);
  }
  __syncthreads();

  for (int r = 0; r < 6; ++r) {
    const char* hb  = sm + (r & 1) * 8192;
    char* hbn       = sm + ((r + 1) & 1) * 8192;
    const char* gbr = sm + GI0 + (r & 1) * 24576;

    uintptr_t pa = (uintptr_t)whh_pk;
    asm volatile("" : "+v"(pa));        // defeat cross-step load hoisting
    const char* pkb = (const char*)pa + w * 49152 + lane * 16;

    f32x4 acc[6];
#pragma unroll
    for (int nf = 0; nf < 6; ++nf) acc[nf] = (f32x4){0.f, 0.f, 0.f, 0.f};

#pragma unroll
    for (int ks = 0; ks < 8; ++ks) {
      const int slot = ks % 3;
      bf16x8 a = lds_frag(hb, l15 * 512 +
                          ((ks * 64 + (lane >> 4) * 16) ^ ((l15 & 7) << 4)));
#pragma unroll
      for (int nf = 0; nf < 6; ++nf) acc[nf] = MFMA16(a, bP[slot][nf], acc[nf]);
      {
        const int nk = (ks + 3) & 7;    // circular: 5,6,7 refill next step's 0,1,2
#pragma unroll
        for (int nf = 0; nf < 6; ++nf)
          bP[slot][nf] = *(const bf16x8*)(pkb + nf * 8192 + nk * 1024);
      }
    }

    if (r + 1 < 6) {
#pragma unroll
      for (int i = 0; i < 3; ++i) {
        int chunk = w * 3 + i;
        gld_lds16(gib + (size_t)((r + 1) * 448 + n0) * 768 + chunk * 512 + lane * 8,
                  sm + GI0 + ((r + 1) & 1) * 24576 + chunk * 1024);
      }
    }

#pragma unroll
    for (int r4 = 0; r4 < 4; ++r4) {
      int seq = seq0 + r4;
      float ir0 = bf2f(*(const u16*)(gbr + (size_t)(seq * 768 + hc0) * 2));
      float iz0 = bf2f(*(const u16*)(gbr + (size_t)(seq * 768 + 256 + hc0) * 2));
      float in0 = bf2f(*(const u16*)(gbr + (size_t)(seq * 768 + 512 + hc0) * 2));
      float ir1 = bf2f(*(const u16*)(gbr + (size_t)(seq * 768 + hc1) * 2));
      float iz1 = bf2f(*(const u16*)(gbr + (size_t)(seq * 768 + 256 + hc1) * 2));
      float in1 = bf2f(*(const u16*)(gbr + (size_t)(seq * 768 + 512 + hc1) * 2));
      {
        float rg = fast_sigmoid(ir0 + acc[0][r4] + br0);
        float zg = fast_sigmoid(iz0 + acc[2][r4] + bz0);
        float ng = fast_tanh(in0 + rg * (acc[4][r4] + bn0));
        float hnew = (1.f - zg) * ng + zg * hold[0][r4];
        hold[0][r4] = hnew;
        u16 hb16 = f2bf(hnew);
        *(u16*)(hbn + seq * 512 + ((hc0 * 2) ^ ((seq & 7) << 4))) = hb16;
        ctxb[(size_t)(r * 448 + n0 + seq) * 256 + hc0] = hb16;
      }
      {
        float rg = fast_sigmoid(ir1 + acc[1][r4] + br1);
        float zg = fast_sigmoid(iz1 + acc[3][r4] + bz1);
        float ng = fast_tanh(in1 + rg * (acc[5][r4] + bn1));
        float hnew = (1.f - zg) * ng + zg * hold[1][r4];
        hold[1][r4] = hnew;
        u16 hb16 = f2bf(hnew);
        *(u16*)(hbn + seq * 512 + ((hc1 * 2) ^ ((seq & 7) << 4))) = hb16;
        ctxb[(size_t)(r * 448 + n0 + seq) * 256 + hc1] = hb16;
      }
    }
    __syncthreads();   // single barrier/step: drains gi[r+1] + hbn writes
  }
}

// ---------------------------------------------------------------------------
// Fused preds+dots+loss (round-14, unchanged): static MF, cross-chunk W
// prefetch, E preload before barrier, diagonal-positive loss epilogue.
// ---------------------------------------------------------------------------
template<int MF>
__device__ __forceinline__ void pd_body(
    int b, int s, int Ms, int t, int lane, int w, char* sm,
    const u16* __restrict__ ctxb, const u16* __restrict__ wkwpk,
    const float* __restrict__ wk_b, const u16* __restrict__ epk,
    const int* __restrict__ neg_rows, const int* __restrict__ neg_cols,
    float* __restrict__ out)
{
  const int PT_OFF = 24576;

#pragma unroll
  for (int j = 0; j < 6; ++j) {
    int u = j * 256 + t;
    int row = u >> 5, slot = u & 31;
    int rr = row < Ms ? row : 0;
    int r = rr / 7, c = rr - r * 7;
    uint4 v = *(const uint4*)&ctxb[((size_t)(r * 448 + b * 7 + c)) * 256 + slot * 8];
    int off = row * 512 + ((slot * 16) ^ ((row & 7) << 4));
    *(uint4*)(sm + off) = v;
  }
  __syncthreads();

  bf16x8 a1[MF][8];
#pragma unroll
  for (int m = 0; m < MF; ++m)
#pragma unroll
    for (int ks = 0; ks < 8; ++ks) {
      int row = m * 16 + (lane & 15);
      int kb  = (ks * 64 + (lane >> 4) * 16) ^ ((row & 7) << 4);
      a1[m][ks] = lds_frag(sm, row * 512 + kb);
    }

  f32x4 acc2[MF];
#pragma unroll
  for (int m = 0; m < MF; ++m) acc2[m] = (f32x4){0.f, 0.f, 0.f, 0.f};

  const char* wfB = (const char*)wkwpk + ((size_t)(s * 20) * 4 + w) * 8192 + lane * 16;
  const char* efB = (const char*)epk   + ((size_t)(b * 20) * 4 + w) * 2048 + lane * 16;
  const int colL = w * 16 + (lane & 15);

  bf16x8 wF[8];
#pragma unroll
  for (int ks = 0; ks < 8; ++ks)
    wF[ks] = *(const bf16x8*)(wfB + ks * 1024);

  for (int ch = 0; ch < 20; ++ch) {
    char* pt = sm + PT_OFF + (ch & 1) * 6144;

    f32x4 acc1[MF];
#pragma unroll
    for (int m = 0; m < MF; ++m) acc1[m] = (f32x4){0.f, 0.f, 0.f, 0.f};
#pragma unroll
    for (int ks = 0; ks < 8; ++ks) {
#pragma unroll
      for (int m = 0; m < MF; ++m) acc1[m] = MFMA16(a1[m][ks], wF[ks], acc1[m]);
    }
    if (ch + 1 < 20) {
      const char* wfn = wfB + (size_t)(ch + 1) * 4 * 8192;
#pragma unroll
      for (int ks = 0; ks < 8; ++ks)
        wF[ks] = *(const bf16x8*)(wfn + ks * 1024);
    }
    {
      float bias = wk_b[s * 1280 + ch * 64 + colL];
#pragma unroll
      for (int m = 0; m < MF; ++m)
#pragma unroll
        for (int r4 = 0; r4 < 4; ++r4) {
          float p = acc1[m][r4] + bias;
          p = fminf(fmaxf(p, -1.f), 1.f);
          int prow = m * 16 + (lane >> 4) * 4 + r4;
          *(u16*)(pt + prow * 128 + ((colL * 2) ^ ((prow & 7) << 4))) = f2bf(p);
        }
    }
    const char* ef = efB + (size_t)ch * 4 * 2048;
    bf16x8 e0 = *(const bf16x8*)ef;
    bf16x8 e1 = *(const bf16x8*)(ef + 1024);
    __syncthreads();   // Pt[ch&1] visible (the only barrier per chunk)

#pragma unroll
    for (int m = 0; m < MF; ++m) {
      int prow = m * 16 + (lane & 15);
      bf16x8 pf0 = lds_frag(pt, prow * 128 +
                            (((lane >> 4) * 16) ^ ((prow & 7) << 4)));
      acc2[m] = MFMA16(pf0, e0, acc2[m]);
      bf16x8 pf1 = lds_frag(pt, prow * 128 +
                            ((64 + (lane >> 4) * 16) ^ ((prow & 7) << 4)));
      acc2[m] = MFMA16(pf1, e1, acc2[m]);
    }
  }

  float* dtile = (float*)sm;
#pragma unroll
  for (int m = 0; m < MF; ++m)
#pragma unroll
    for (int r4 = 0; r4 < 4; ++r4) {
      int row = m * 16 + (lane >> 4) * 4 + r4;
      int q = w * 16 + (lane & 15);
      dtile[row * 65 + q] = acc2[m][r4];
    }
  __syncthreads();

  if (w == 0) {
    float lsum = 0.f, csum = 0.f;
    if (lane < Ms) {
      int rr = lane;
      int r = rr / 7, c = rr - r * 7;
      const float* drow = &dtile[rr * 65];
      float d0 = drow[rr];
      const int nbase = (((b * 5 + s) * 6 + r) * 7 + c) * 16;
      float mx = d0;
      float d[16];
#pragma unroll
      for (int j = 0; j < 16; ++j) {
        int q = neg_rows[nbase + j] * 7 + neg_cols[nbase + j];
        d[j] = drow[q];
        mx = fmaxf(mx, d[j]);
      }
      float se = fast_exp(d0 - mx);
#pragma unroll
      for (int j = 0; j < 16; ++j) se += fast_exp(d[j] - mx);
      lsum = -(d0 - mx - fast_log(se));
      csum = (d0 >= mx) ? 1.f : 0.f;
    }
#pragma unroll
    for (int off = 32; off > 0; off >>= 1) {
      lsum += __shfl_down(lsum, off);
      csum += __shfl_down(csum, off);
    }
    if (lane == 0) {
      atomicAdd(&out[0], lsum * (1.f / 8960.f));
      atomicAdd(&out[1], csum * (1.f / 8960.f));
    }
  }
}

__global__ __launch_bounds__(256) void fused_pd(
    const u16* __restrict__ ctxb, const u16* __restrict__ wkwpk,
    const float* __restrict__ wk_b, const u16* __restrict__ epk,
    const int* __restrict__ neg_rows, const int* __restrict__ neg_cols,
    float* __restrict__ out)
{
  const int b = blockIdx.x;
  const int s = blockIdx.y;
  const int Ms = (6 - s) * 7;
  const int t = threadIdx.x;
  const int lane = t & 63, w = t >> 6;

  __shared__ uint4 smem4[36864 / 16];   // ctx/dots 24576 | Pt dbuf 2x6144
  char* sm = (char*)smem4;

  if (s < 2)      pd_body<3>(b, s, Ms, t, lane, w, sm, ctxb, wkwpk, wk_b, epk,
                             neg_rows, neg_cols, out);
  else if (s < 4) pd_body<2>(b, s, Ms, t, lane, w, sm, ctxb, wkwpk, wk_b, epk,
                             neg_rows, neg_cols, out);
  else            pd_body<1>(b, s, Ms, t, lane, w, sm, ctxb, wkwpk, wk_b, epk,
                             neg_rows, neg_cols, out);
}

// ---------------------------------------------------------------------------
extern "C" void kernel_launch(void* const* d_in, const int* in_sizes, int n_in,
                              void* d_out, int out_size, void* d_ws, size_t ws_size,
                              hipStream_t stream)
{
  const float* enc    = (const float*)d_in[0];
  const float* hidden = (const float*)d_in[1];
  const float* w_ih   = (const float*)d_in[2];
  const float* w_hh   = (const float*)d_in[3];
  const float* b_ih   = (const float*)d_in[4];
  const float* b_hh   = (const float*)d_in[5];
  const float* wk_w   = (const float*)d_in[6];
  const float* wk_b   = (const float*)d_in[7];
  const int* neg_rows = (const int*)d_in[8];
  const int* neg_cols = (const int*)d_in[9];
  float* out = (float*)d_out;

  u16*   gib   = (u16*)d_ws;                        // [6*448][768] bf16
  u16*   ctxb  = gib + 6 * 448 * 768;               // [6*448][256] bf16
  u16*   whhpk = ctxb + 6 * 448 * 256;              // 196608 bf16
  u16*   wkwpk = whhpk + 24576 * 8;                 // 1638400 bf16
  u16*   epk   = wkwpk + 204800 * 8;                // 5242880 bf16
  u16*   enc2  = epk + 655360 * 8;                  // 3440640 bf16
  u16*   wih2  = enc2 + 430080 * 8;                 // 983040 bf16

  packA<<<2160, 256, 0, stream>>>(enc, w_ih, enc2, wih2, out);

  gi_packB<<<3582, 256, 0, stream>>>(enc2, wih2, b_ih, gib,
                                     w_hh, wk_w, enc, whhpk, wkwpk, epk);

  gru_fused<<<28, 512, 0, stream>>>(whhpk, b_hh, hidden, gib, ctxb);

  fused_pd<<<dim3(64, 5), 256, 0, stream>>>(ctxb, wkwpk, wk_b, epk,
                                            neg_rows, neg_cols, out);
}